// Round 1
// baseline (1082.577 us; speedup 1.0000x reference)
//
#include <hip/hip_runtime.h>
#include <hip/hip_bf16.h>

// Problem dims
constexpr int Bn   = 8;     // batch
constexpr int Cin  = 576;   // input channels = 3*C
constexpr int Cc   = 192;   // output channels
constexpr int KKn  = 9;     // kernel positions (3x3)
constexpr int Hh   = 56;
constexpr int Ww   = 56;
constexpr int HWn  = Hh * Ww;          // 3136
constexpr int CKK  = Cc * KKn;         // 1728

// ---------------------------------------------------------------------------
// Kernel 1: logits[b][o][n] = sum_k fc_w[o][k] * x[b][k][n]
// M=1728, N=3136, K=576. 64x64 block tile, TK=16, 256 threads, 4x4/thread.
// Output stored as bf16.
// ---------------------------------------------------------------------------
__global__ __launch_bounds__(256) void gemm_logits_kernel(
    const float* __restrict__ x, const float* __restrict__ fcw,
    __hip_bfloat16* __restrict__ logits)
{
    __shared__ float As[16][68];  // [k][m], padded (68) to avoid bank conflicts
    __shared__ float Bs[16][68];  // [k][n]

    const int n0 = blockIdx.x * 64;   // 49 tiles
    const int m0 = blockIdx.y * 64;   // 27 tiles
    const int b  = blockIdx.z;        // 8
    const int tid = threadIdx.x;
    const int tx = tid & 15, ty = tid >> 4;

    const float* xb = x + (size_t)b * Cin * HWn;

    float acc[4][4] = {};

    // Staging maps
    const int am = tid >> 2;            // 0..63 (A row within tile)
    const int ak = (tid & 3) * 4;       // 0,4,8,12 (A k quad)
    const int bk = tid >> 4;            // 0..15  (B k row)
    const int bn = (tid & 15) * 4;      // B col quad

    for (int k0 = 0; k0 < Cin; k0 += 16) {
        float4 av = *(const float4*)&fcw[(size_t)(m0 + am) * Cin + k0 + ak];
        float4 bv = *(const float4*)&xb[(size_t)(k0 + bk) * HWn + n0 + bn];
        __syncthreads();   // previous iteration's reads complete
        As[ak + 0][am] = av.x;
        As[ak + 1][am] = av.y;
        As[ak + 2][am] = av.z;
        As[ak + 3][am] = av.w;
        *(float4*)&Bs[bk][bn] = bv;
        __syncthreads();
#pragma unroll
        for (int kk = 0; kk < 16; kk++) {
            float4 a  = *(const float4*)&As[kk][ty * 4];
            float4 bb = *(const float4*)&Bs[kk][tx * 4];
            acc[0][0] += a.x * bb.x; acc[0][1] += a.x * bb.y;
            acc[0][2] += a.x * bb.z; acc[0][3] += a.x * bb.w;
            acc[1][0] += a.y * bb.x; acc[1][1] += a.y * bb.y;
            acc[1][2] += a.y * bb.z; acc[1][3] += a.y * bb.w;
            acc[2][0] += a.z * bb.x; acc[2][1] += a.z * bb.y;
            acc[2][2] += a.z * bb.z; acc[2][3] += a.z * bb.w;
            acc[3][0] += a.w * bb.x; acc[3][1] += a.w * bb.y;
            acc[3][2] += a.w * bb.z; acc[3][3] += a.w * bb.w;
        }
    }

#pragma unroll
    for (int i = 0; i < 4; i++) {
        const int m = m0 + ty * 4 + i;
        union { ushort4 u; __hip_bfloat16 h[4]; } pk;
        pk.h[0] = __float2bfloat16(acc[i][0]);
        pk.h[1] = __float2bfloat16(acc[i][1]);
        pk.h[2] = __float2bfloat16(acc[i][2]);
        pk.h[3] = __float2bfloat16(acc[i][3]);
        *(ushort4*)&logits[((size_t)b * CKK + m) * HWn + n0 + tx * 4] = pk.u;
    }
}

// ---------------------------------------------------------------------------
// Kernel 2: feat[i][b][c][h][w] = relu( sum_{d,u,v} x[b][3c+d][h+u-1][w+v-1]
//                                        * w1[i][c][d][u][v] )
// One block per (c, row-tile of 8, b); computes all 9 positions from one
// LDS x-tile (3 channels, 10x58 with halo).
// ---------------------------------------------------------------------------
__global__ __launch_bounds__(256) void conv1_kernel(
    const float* __restrict__ x, const float* __restrict__ w1,
    __hip_bfloat16* __restrict__ feat)
{
    const int c  = blockIdx.x;   // 0..191
    const int hb = blockIdx.y;   // 0..6
    const int b  = blockIdx.z;   // 0..7
    const int tid = threadIdx.x;
    const int h0 = hb * 8;

    __shared__ float xt[3][10][58];
    __shared__ float wt[9][27];

    // weights: w1[i][c][d][u][v] at (i*Cc + c)*27 + (d*9 + u*3 + v)
    for (int idx = tid; idx < 9 * 27; idx += 256) {
        int i = idx / 27, j = idx % 27;
        wt[i][j] = w1[(size_t)(i * Cc + c) * 27 + j];
    }
    // x tile with halo
    for (int idx = tid; idx < 3 * 10 * 58; idx += 256) {
        int d = idx / 580, rem = idx % 580;
        int r = rem / 58, cc = rem % 58;
        int h = h0 - 1 + r, w = cc - 1;
        float v = 0.f;
        if (h >= 0 && h < Hh && w >= 0 && w < Ww)
            v = x[((size_t)(b * Cin + 3 * c + d) * Hh + h) * Ww + w];
        xt[d][r][cc] = v;
    }
    __syncthreads();

#pragma unroll
    for (int i = 0; i < 9; i++) {
        for (int p = tid; p < 8 * 56; p += 256) {
            int r = p / 56, w = p % 56;
            float s = 0.f;
#pragma unroll
            for (int d = 0; d < 3; d++)
#pragma unroll
                for (int u = 0; u < 3; u++)
#pragma unroll
                    for (int v = 0; v < 3; v++)
                        s += xt[d][r + u][w + v] * wt[i][d * 9 + u * 3 + v];
            s = fmaxf(s, 0.f);
            feat[(((size_t)i * Bn + b) * Cc + c) * HWn + (h0 + r) * Ww + w] =
                __float2bfloat16(s);
        }
    }
}

// ---------------------------------------------------------------------------
// Kernel 3: softmax over i of logits + depthwise conv2 + weighted sum.
// out[b][c][h][w] = sum_i attn_i * sum_{u,v} feat[i][b][c][h+u-1][w+v-1]
//                                           * w2[i][c][u][v]
// ---------------------------------------------------------------------------
__global__ __launch_bounds__(256) void conv2_agg_kernel(
    const __hip_bfloat16* __restrict__ feat,
    const __hip_bfloat16* __restrict__ logits,
    const float* __restrict__ w2, float* __restrict__ out)
{
    const int c  = blockIdx.x;
    const int hb = blockIdx.y;
    const int b  = blockIdx.z;
    const int tid = threadIdx.x;
    const int h0 = hb * 8;

    __shared__ __hip_bfloat16 ft[9][10][58];
    __shared__ float wt[9][9];

    for (int idx = tid; idx < 9 * 9; idx += 256) {
        int i = idx / 9, j = idx % 9;
        wt[i][j] = w2[(size_t)(i * Cc + c) * 9 + j];
    }
    for (int idx = tid; idx < 9 * 10 * 58; idx += 256) {
        int i = idx / 580, rem = idx % 580;
        int r = rem / 58, cc = rem % 58;
        int h = h0 - 1 + r, w = cc - 1;
        __hip_bfloat16 v = __float2bfloat16(0.f);
        if (h >= 0 && h < Hh && w >= 0 && w < Ww)
            v = feat[(((size_t)i * Bn + b) * Cc + c) * HWn + h * Ww + w];
        ft[i][r][cc] = v;
    }
    __syncthreads();

    for (int p = tid; p < 8 * 56; p += 256) {
        int r = p / 56, w = p % 56;
        int hw = (h0 + r) * Ww + w;

        // softmax over the 9 positions
        float lg[9];
#pragma unroll
        for (int i = 0; i < 9; i++)
            lg[i] = __bfloat162float(logits[((size_t)b * CKK + c * 9 + i) * HWn + hw]);
        float mx = lg[0];
#pragma unroll
        for (int i = 1; i < 9; i++) mx = fmaxf(mx, lg[i]);
        float sum = 0.f;
#pragma unroll
        for (int i = 0; i < 9; i++) { lg[i] = __expf(lg[i] - mx); sum += lg[i]; }
        float inv = 1.f / sum;

        float o = 0.f;
#pragma unroll
        for (int i = 0; i < 9; i++) {
            float s = 0.f;
#pragma unroll
            for (int u = 0; u < 3; u++)
#pragma unroll
                for (int v = 0; v < 3; v++)
                    s += __bfloat162float(ft[i][r + u][w + v]) * wt[i][u * 3 + v];
            o += s * lg[i];
        }
        out[((size_t)(b * Cc + c)) * HWn + hw] = o * inv;
    }
}

// ---------------------------------------------------------------------------
extern "C" void kernel_launch(void* const* d_in, const int* in_sizes, int n_in,
                              void* d_out, int out_size, void* d_ws, size_t ws_size,
                              hipStream_t stream)
{
    const float* x    = (const float*)d_in[0];
    const float* fc_w = (const float*)d_in[1];
    const float* w1   = (const float*)d_in[2];
    const float* w2   = (const float*)d_in[3];
    float* out = (float*)d_out;

    // Workspace layout (bf16): logits (b,o,hw) then feat (i,b,c,h,w)
    __hip_bfloat16* logits = (__hip_bfloat16*)d_ws;
    __hip_bfloat16* feat   = logits + (size_t)Bn * CKK * HWn;

    gemm_logits_kernel<<<dim3(HWn / 64, CKK / 64, Bn), 256, 0, stream>>>(x, fc_w, logits);
    conv1_kernel<<<dim3(Cc, Hh / 8, Bn), 256, 0, stream>>>(x, w1, feat);
    conv2_agg_kernel<<<dim3(Cc, Hh / 8, Bn), 256, 0, stream>>>(feat, logits, w2, out);
}

// Round 2
// 484.559 us; speedup vs baseline: 2.2341x; 2.2341x over previous
//
#include <hip/hip_runtime.h>
#include <hip/hip_bf16.h>

// Problem dims
constexpr int Bn   = 8;
constexpr int Cin  = 576;
constexpr int Cc   = 192;
constexpr int Hh   = 56;
constexpr int Ww   = 56;
constexpr int HWn  = Hh * Ww;          // 3136
constexpr int CKK  = Cc * 9;           // 1728

// GEMM dims (batch folded into N)
constexpr int GM = 1792;               // 1728 padded to 14*128
constexpr int GK = 576;
constexpr int GN = Bn * HWn;           // 25088 = 196*128

using f16x8 = __attribute__((ext_vector_type(8))) _Float16;
using f32x4 = __attribute__((ext_vector_type(4))) float;

__device__ __forceinline__ void async_copy16(void* lds, const void* gptr) {
    __builtin_amdgcn_global_load_lds(
        (const __attribute__((address_space(1))) unsigned int*)gptr,
        (__attribute__((address_space(3))) unsigned int*)lds, 16, 0, 0);
}

// ---------------------------------------------------------------------------
// fc_w (1728x576 f32) -> fcw16 (1792x576 f16, pad rows zero)
// ---------------------------------------------------------------------------
__global__ __launch_bounds__(256) void cast_fcw_kernel(
    const float* __restrict__ fcw, _Float16* __restrict__ out)
{
    int idx = blockIdx.x * 256 + threadIdx.x;
    int e = idx * 4;
    if (e >= GM * GK) return;
    int row = e / GK;                      // 576 % 4 == 0 -> row uniform in group
    union { ushort4 u; _Float16 h[4]; } pk;
    if (row < CKK) {
        float4 v = *(const float4*)&fcw[e];
        pk.h[0] = (_Float16)v.x; pk.h[1] = (_Float16)v.y;
        pk.h[2] = (_Float16)v.z; pk.h[3] = (_Float16)v.w;
    } else {
        pk.h[0] = pk.h[1] = pk.h[2] = pk.h[3] = (_Float16)0.f;
    }
    *(ushort4*)&out[e] = pk.u;
}

// ---------------------------------------------------------------------------
// x[b][k][hw] f32 -> xt[b*HW + hw][k] f16  (K-contiguous for NT GEMM)
// 32(k) x 64(hw) tiles via LDS
// ---------------------------------------------------------------------------
__global__ __launch_bounds__(256) void transpose_cast_kernel(
    const float* __restrict__ x, _Float16* __restrict__ xt)
{
    __shared__ float t[32][65];
    const int b = blockIdx.z, k0 = blockIdx.y * 32, hw0 = blockIdx.x * 64;
    const int tid = threadIdx.x;
    const int col = tid & 63, kr = tid >> 6;
#pragma unroll
    for (int p = 0; p < 8; p++) {
        int k = kr + p * 4;
        t[k][col] = x[(size_t)(b * Cin + k0 + k) * HWn + hw0 + col];
    }
    __syncthreads();
    const int row = tid >> 2, cq = (tid & 3) * 8;
    union { uint4 u; _Float16 h[8]; } pk;
#pragma unroll
    for (int j = 0; j < 8; j++) pk.h[j] = (_Float16)t[cq + j][row];
    *(uint4*)&xt[(size_t)(b * HWn + hw0 + row) * GK + k0 + cq] = pk.u;
}

// ---------------------------------------------------------------------------
// MFMA GEMM: logits[b][m][hw] = sum_k fcw[m][k] * x[b][k][hw]
// A = fcw16 [GM][GK], B = xt [GN][GK] (both K-contiguous), C -> bf16 logits.
// 128x128 block tile, BK=32, 4 waves x (64x64), 16x16x32 f16 MFMA.
// ---------------------------------------------------------------------------
__global__ __launch_bounds__(256) void gemm_mfma_kernel(
    const _Float16* __restrict__ A, const _Float16* __restrict__ Bm,
    __hip_bfloat16* __restrict__ logits)
{
    __shared__ _Float16 As[128 * 32];
    __shared__ _Float16 Bs[128 * 32];

    const int tid = threadIdx.x;
    const int n0 = blockIdx.x * 128;
    const int m0 = blockIdx.y * 128;
    const int lane = tid & 63;
    const int wave = tid >> 6;
    const int wm = (wave >> 1) * 64;
    const int wn = (wave & 1) * 64;
    const int lm = lane & 15;
    const int kq = (lane >> 4) * 8;

    // staging map: thread t covers 16B chunk t -> row t>>2, k-offset (t&3)*8
    const int r0 = tid >> 2;
    const int c0 = (tid & 3) * 8;

    f32x4 acc[4][4] = {};

    for (int k0 = 0; k0 < GK; k0 += 32) {
        async_copy16(&As[r0 * 32 + c0],        &A[(size_t)(m0 + r0) * GK + k0 + c0]);
        async_copy16(&As[(64 + r0) * 32 + c0], &A[(size_t)(m0 + 64 + r0) * GK + k0 + c0]);
        async_copy16(&Bs[r0 * 32 + c0],        &Bm[(size_t)(n0 + r0) * GK + k0 + c0]);
        async_copy16(&Bs[(64 + r0) * 32 + c0], &Bm[(size_t)(n0 + 64 + r0) * GK + k0 + c0]);
        __syncthreads();
        f16x8 af[4], bf[4];
#pragma unroll
        for (int i = 0; i < 4; i++) {
            af[i] = *(const f16x8*)&As[(wm + i * 16 + lm) * 32 + kq];
            bf[i] = *(const f16x8*)&Bs[(wn + i * 16 + lm) * 32 + kq];
        }
#pragma unroll
        for (int i = 0; i < 4; i++)
#pragma unroll
            for (int j = 0; j < 4; j++)
                acc[i][j] = __builtin_amdgcn_mfma_f32_16x16x32_f16(af[i], bf[j], acc[i][j], 0, 0, 0);
        __syncthreads();
    }

    // C/D: col = lane&15, row = (lane>>4)*4 + reg
#pragma unroll
    for (int j = 0; j < 4; j++) {
        int n = n0 + wn + j * 16 + lm;
        int b = n / HWn, hw = n % HWn;
#pragma unroll
        for (int i = 0; i < 4; i++) {
            int mbase = m0 + wm + i * 16 + (lane >> 4) * 4;
#pragma unroll
            for (int r = 0; r < 4; r++) {
                int m = mbase + r;
                if (m < CKK)
                    logits[((size_t)b * CKK + m) * HWn + hw] = __float2bfloat16(acc[i][j][r]);
            }
        }
    }
}

// ---------------------------------------------------------------------------
// conv1: feat[i][b][c][h][w] = relu(sum_{d,u,v} x[b][3c+d][h+u-1][w+v-1]*w1[i][c][d][u][v])
// Window in VGPRs (27 LDS reads/px); weights block-uniform -> s_load.
// ---------------------------------------------------------------------------
__global__ __launch_bounds__(256) void conv1_kernel(
    const float* __restrict__ x, const float* __restrict__ w1,
    __hip_bfloat16* __restrict__ feat)
{
    const int c = blockIdx.x, hb = blockIdx.y, b = blockIdx.z;
    const int tid = threadIdx.x;
    const int h0 = hb * 8;
    __shared__ float xt[3][10][58];

    for (int idx = tid; idx < 3 * 580; idx += 256) {
        int d = idx / 580, rem = idx % 580, r = rem / 58, cc = rem % 58;
        int h = h0 - 1 + r, w = cc - 1;
        float v = 0.f;
        if (h >= 0 && h < Hh && w >= 0 && w < Ww)
            v = x[((size_t)(b * Cin + 3 * c + d) * Hh + h) * Ww + w];
        xt[d][r][cc] = v;
    }
    __syncthreads();

    const float* wbase = w1 + (size_t)c * 27;
    for (int p = tid; p < 448; p += 256) {
        int r = p / 56, w = p % 56;
        float win[27];
#pragma unroll
        for (int d = 0; d < 3; d++)
#pragma unroll
            for (int u = 0; u < 3; u++)
#pragma unroll
                for (int v = 0; v < 3; v++)
                    win[d * 9 + u * 3 + v] = xt[d][r + u][w + v];
#pragma unroll
        for (int i = 0; i < 9; i++) {
            const float* wp = wbase + (size_t)i * Cc * 27;
            float s = 0.f;
#pragma unroll
            for (int j = 0; j < 27; j++) s += win[j] * wp[j];
            s = fmaxf(s, 0.f);
            feat[(((size_t)i * Bn + b) * Cc + c) * HWn + (h0 + r) * Ww + w] =
                __float2bfloat16(s);
        }
    }
}

// ---------------------------------------------------------------------------
// conv2 + softmax + aggregation. 2 rows per thread (window-row sharing).
// ---------------------------------------------------------------------------
__global__ __launch_bounds__(256) void conv2_agg_kernel(
    const __hip_bfloat16* __restrict__ feat,
    const __hip_bfloat16* __restrict__ logits,
    const float* __restrict__ w2, float* __restrict__ out)
{
    const int c = blockIdx.x, hb = blockIdx.y, b = blockIdx.z;
    const int tid = threadIdx.x;
    const int h0 = hb * 8;
    __shared__ __hip_bfloat16 ft[9][10][58];

    const __hip_bfloat16 z = __float2bfloat16(0.f);
    for (int idx = tid; idx < 9 * 580; idx += 256) {
        int i = idx / 580, rem = idx % 580, r = rem / 58, cc = rem % 58;
        int h = h0 - 1 + r, w = cc - 1;
        __hip_bfloat16 v = z;
        if (h >= 0 && h < Hh && w >= 0 && w < Ww)
            v = feat[(((size_t)i * Bn + b) * Cc + c) * HWn + h * Ww + w];
        ft[i][r][cc] = v;
    }
    __syncthreads();

    if (tid < 224) {
        const int r = (tid / 56) * 2, w = tid % 56;
        const int hw0 = (h0 + r) * Ww + w, hw1 = hw0 + Ww;

        const __hip_bfloat16* lbase = logits + ((size_t)b * CKK + c * 9) * HWn;
        float lg0[9], lg1[9];
#pragma unroll
        for (int i = 0; i < 9; i++) {
            lg0[i] = __bfloat162float(lbase[(size_t)i * HWn + hw0]);
            lg1[i] = __bfloat162float(lbase[(size_t)i * HWn + hw1]);
        }
        float mx0 = lg0[0], mx1 = lg1[0];
#pragma unroll
        for (int i = 1; i < 9; i++) { mx0 = fmaxf(mx0, lg0[i]); mx1 = fmaxf(mx1, lg1[i]); }
        float s0 = 0.f, s1 = 0.f;
#pragma unroll
        for (int i = 0; i < 9; i++) {
            lg0[i] = __expf(lg0[i] - mx0); s0 += lg0[i];
            lg1[i] = __expf(lg1[i] - mx1); s1 += lg1[i];
        }

        float o0 = 0.f, o1 = 0.f;
#pragma unroll
        for (int i = 0; i < 9; i++) {
            const float* wp = w2 + ((size_t)i * Cc + c) * 9;
            float f0 = 0.f, f1 = 0.f;
#pragma unroll
            for (int u = 0; u < 3; u++)
#pragma unroll
                for (int v = 0; v < 3; v++) {
                    float wv = wp[u * 3 + v];
                    f0 += __bfloat162float(ft[i][r + u][w + v]) * wv;
                    f1 += __bfloat162float(ft[i][r + 1 + u][w + v]) * wv;
                }
            o0 += f0 * lg0[i];
            o1 += f1 * lg1[i];
        }
        out[((size_t)(b * Cc + c)) * HWn + hw0] = o0 / s0;
        out[((size_t)(b * Cc + c)) * HWn + hw1] = o1 / s1;
    }
}

// ---------------------------------------------------------------------------
extern "C" void kernel_launch(void* const* d_in, const int* in_sizes, int n_in,
                              void* d_out, int out_size, void* d_ws, size_t ws_size,
                              hipStream_t stream)
{
    const float* x    = (const float*)d_in[0];
    const float* fc_w = (const float*)d_in[1];
    const float* w1   = (const float*)d_in[2];
    const float* w2   = (const float*)d_in[3];
    float* out = (float*)d_out;

    // ws layout: [logits bf16 86.7MB][feat bf16 86.7MB]; xt+fcw16 alias the
    // feat region (dead before conv1 writes feat; stream order serializes).
    char* ws = (char*)d_ws;
    __hip_bfloat16* logits = (__hip_bfloat16*)ws;
    char* region2 = ws + (size_t)Bn * CKK * HWn * 2;
    __hip_bfloat16* feat = (__hip_bfloat16*)region2;
    _Float16* xt    = (_Float16*)region2;
    _Float16* fcw16 = (_Float16*)(region2 + (size_t)GN * GK * 2);

    cast_fcw_kernel<<<(GM * GK / 4 + 255) / 256, 256, 0, stream>>>(fc_w, fcw16);
    transpose_cast_kernel<<<dim3(HWn / 64, GK / 32, Bn), 256, 0, stream>>>(x, xt);
    gemm_mfma_kernel<<<dim3(GN / 128, GM / 128), 256, 0, stream>>>(fcw16, xt, logits);
    conv1_kernel<<<dim3(Cc, Hh / 8, Bn), 256, 0, stream>>>(x, w1, feat);
    conv2_agg_kernel<<<dim3(Cc, Hh / 8, Bn), 256, 0, stream>>>(feat, logits, w2, out);
}

// Round 3
// 292.285 us; speedup vs baseline: 3.7038x; 1.6578x over previous
//
#include <hip/hip_runtime.h>
#include <hip/hip_bf16.h>

// Problem dims
constexpr int Bn   = 8;
constexpr int Cin  = 576;
constexpr int Cc   = 192;
constexpr int Hh   = 56;
constexpr int Ww   = 56;
constexpr int HWn  = Hh * Ww;          // 3136
constexpr int CKK  = Cc * 9;           // 1728

// GEMM dims (batch folded into N)
constexpr int GM = 1792;               // 1728 padded
constexpr int GK = 576;
constexpr int GN = Bn * HWn;           // 25088

using f16x8 = __attribute__((ext_vector_type(8))) _Float16;
using f32x4 = __attribute__((ext_vector_type(4))) float;

__device__ __forceinline__ void async_copy16(void* lds, const void* gptr) {
    __builtin_amdgcn_global_load_lds(
        (const __attribute__((address_space(1))) unsigned int*)gptr,
        (__attribute__((address_space(3))) unsigned int*)lds, 16, 0, 0);
}

__device__ __forceinline__ float blo(unsigned int u) { return __uint_as_float(u << 16); }
__device__ __forceinline__ float bhi(unsigned int u) { return __uint_as_float(u & 0xffff0000u); }

// ---------------------------------------------------------------------------
// fc_w (1728x576 f32) -> fcw16 (1792x576 f16, pad rows zero)
// ---------------------------------------------------------------------------
__global__ __launch_bounds__(256) void cast_fcw_kernel(
    const float* __restrict__ fcw, _Float16* __restrict__ out)
{
    int idx = blockIdx.x * 256 + threadIdx.x;
    int e = idx * 4;
    if (e >= GM * GK) return;
    int row = e / GK;
    union { ushort4 u; _Float16 h[4]; } pk;
    if (row < CKK) {
        float4 v = *(const float4*)&fcw[e];
        pk.h[0] = (_Float16)v.x; pk.h[1] = (_Float16)v.y;
        pk.h[2] = (_Float16)v.z; pk.h[3] = (_Float16)v.w;
    } else {
        pk.h[0] = pk.h[1] = pk.h[2] = pk.h[3] = (_Float16)0.f;
    }
    *(ushort4*)&out[e] = pk.u;
}

// ---------------------------------------------------------------------------
// x[b][k][hw] f32 -> xt[b*HW + hw][k] f16
// ---------------------------------------------------------------------------
__global__ __launch_bounds__(256) void transpose_cast_kernel(
    const float* __restrict__ x, _Float16* __restrict__ xt)
{
    __shared__ float t[32][65];
    const int b = blockIdx.z, k0 = blockIdx.y * 32, hw0 = blockIdx.x * 64;
    const int tid = threadIdx.x;
    const int col = tid & 63, kr = tid >> 6;
#pragma unroll
    for (int p = 0; p < 8; p++) {
        int k = kr + p * 4;
        t[k][col] = x[(size_t)(b * Cin + k0 + k) * HWn + hw0 + col];
    }
    __syncthreads();
    const int row = tid >> 2, cq = (tid & 3) * 8;
    union { uint4 u; _Float16 h[8]; } pk;
#pragma unroll
    for (int j = 0; j < 8; j++) pk.h[j] = (_Float16)t[cq + j][row];
    *(uint4*)&xt[(size_t)(b * HWn + hw0 + row) * GK + k0 + cq] = pk.u;
}

// ---------------------------------------------------------------------------
// MFMA GEMM: logits[b][m][hw] = sum_k fcw[m][k] * x[b][k][hw]  (bf16 out)
// ---------------------------------------------------------------------------
__global__ __launch_bounds__(256) void gemm_mfma_kernel(
    const _Float16* __restrict__ A, const _Float16* __restrict__ Bm,
    __hip_bfloat16* __restrict__ logits)
{
    __shared__ _Float16 As[128 * 32];
    __shared__ _Float16 Bs[128 * 32];

    const int tid = threadIdx.x;
    const int n0 = blockIdx.x * 128;
    const int m0 = blockIdx.y * 128;
    const int lane = tid & 63;
    const int wave = tid >> 6;
    const int wm = (wave >> 1) * 64;
    const int wn = (wave & 1) * 64;
    const int lm = lane & 15;
    const int kq = (lane >> 4) * 8;

    const int r0 = tid >> 2;
    const int c0 = (tid & 3) * 8;

    f32x4 acc[4][4] = {};

    for (int k0 = 0; k0 < GK; k0 += 32) {
        async_copy16(&As[r0 * 32 + c0],        &A[(size_t)(m0 + r0) * GK + k0 + c0]);
        async_copy16(&As[(64 + r0) * 32 + c0], &A[(size_t)(m0 + 64 + r0) * GK + k0 + c0]);
        async_copy16(&Bs[r0 * 32 + c0],        &Bm[(size_t)(n0 + r0) * GK + k0 + c0]);
        async_copy16(&Bs[(64 + r0) * 32 + c0], &Bm[(size_t)(n0 + 64 + r0) * GK + k0 + c0]);
        __syncthreads();
        f16x8 af[4], bf[4];
#pragma unroll
        for (int i = 0; i < 4; i++) {
            af[i] = *(const f16x8*)&As[(wm + i * 16 + lm) * 32 + kq];
            bf[i] = *(const f16x8*)&Bs[(wn + i * 16 + lm) * 32 + kq];
        }
#pragma unroll
        for (int i = 0; i < 4; i++)
#pragma unroll
            for (int j = 0; j < 4; j++)
                acc[i][j] = __builtin_amdgcn_mfma_f32_16x16x32_f16(af[i], bf[j], acc[i][j], 0, 0, 0);
        __syncthreads();
    }

#pragma unroll
    for (int j = 0; j < 4; j++) {
        int n = n0 + wn + j * 16 + lm;
        int b = n / HWn, hw = n % HWn;
#pragma unroll
        for (int i = 0; i < 4; i++) {
            int mbase = m0 + wm + i * 16 + (lane >> 4) * 4;
#pragma unroll
            for (int r = 0; r < 4; r++) {
                int m = mbase + r;
                if (m < CKK)
                    logits[((size_t)b * CKK + m) * HWn + hw] = __float2bfloat16(acc[i][j][r]);
            }
        }
    }
}

// ---------------------------------------------------------------------------
// conv1: feat[i][b][c][h][w] = relu(sum_{d,u,v} x[b][3c+d][h+u-1][w+v-1]*w1[i][c][d][u][v])
// 28-row tile; thread = 7-px row strip; window in VGPRs; weights s_loaded.
// ---------------------------------------------------------------------------
__global__ __launch_bounds__(256, 3) void conv1_kernel(
    const float* __restrict__ x, const float* __restrict__ w1,
    __hip_bfloat16* __restrict__ feat)
{
    const int c = blockIdx.x, hb = blockIdx.y, b = blockIdx.z;
    const int tid = threadIdx.x;
    const int h0 = hb * 28;
    __shared__ float xt[3][30][60];   // col = w+1 (cols 0..57 used); stride 60 spreads banks

    // main staging: 3 ch x 30 rows x 14 float4-groups
    for (int idx = tid; idx < 1260; idx += 256) {
        int d = idx / 420, rem = idx - d * 420;
        int r = rem / 14, g = rem - r * 14;
        int h = h0 - 1 + r;
        float4 v = {0.f, 0.f, 0.f, 0.f};
        if (h >= 0 && h < Hh)
            v = *(const float4*)&x[((size_t)(b * Cin + 3 * c + d) * Hh + h) * Ww + 4 * g];
        xt[d][r][1 + 4 * g + 0] = v.x;
        xt[d][r][1 + 4 * g + 1] = v.y;
        xt[d][r][1 + 4 * g + 2] = v.z;
        xt[d][r][1 + 4 * g + 3] = v.w;
    }
    // edge zeros: cols 0 (w=-1) and 57 (w=56)
    for (int idx = tid; idx < 180; idx += 256) {
        int d = idx / 60, rem = idx - d * 60;
        int r = rem >> 1, col = (rem & 1) ? 57 : 0;
        xt[d][r][col] = 0.f;
    }
    __syncthreads();

    if (tid < 224) {
        const int row = tid >> 3, seg = tid & 7;
        const int w0 = seg * 7;

        float win[3][3][9];
#pragma unroll
        for (int d = 0; d < 3; d++)
#pragma unroll
            for (int u = 0; u < 3; u++)
#pragma unroll
                for (int k = 0; k < 9; k++)
                    win[d][u][k] = xt[d][row + u][w0 + k];

        const int hw = (h0 + row) * Ww + w0;
#pragma unroll 1
        for (int i = 0; i < 9; i++) {
            const float* wp = w1 + ((size_t)i * Cc + c) * 27;
            float wgt[27];
#pragma unroll
            for (int j = 0; j < 27; j++) wgt[j] = wp[j];
            float acc[7] = {};
#pragma unroll
            for (int d = 0; d < 3; d++)
#pragma unroll
                for (int u = 0; u < 3; u++)
#pragma unroll
                    for (int v = 0; v < 3; v++) {
                        float wv = wgt[d * 9 + u * 3 + v];
#pragma unroll
                        for (int p = 0; p < 7; p++)
                            acc[p] += win[d][u][p + v] * wv;
                    }
            __hip_bfloat16* fp = feat + (((size_t)i * Bn + b) * Cc + c) * HWn + hw;
#pragma unroll
            for (int p = 0; p < 7; p++)
                fp[p] = __float2bfloat16(fmaxf(acc[p], 0.f));
        }
    }
}

// ---------------------------------------------------------------------------
// conv2 + softmax + aggregation. Thread = 8-px row strip; ft tile stride 72,
// col shift +2 so window rows are one b128+b64 LDS read.
// ---------------------------------------------------------------------------
__global__ __launch_bounds__(256, 3) void conv2_agg_kernel(
    const __hip_bfloat16* __restrict__ feat,
    const __hip_bfloat16* __restrict__ logits,
    const float* __restrict__ w2, float* __restrict__ out)
{
    const int c = blockIdx.x, hb = blockIdx.y, b = blockIdx.z;
    const int tid = threadIdx.x;
    const int h0 = hb * 28;
    __shared__ unsigned short ft[9][30][72];   // col = w+2 (cols 0..59 used)

    // main staging: 9 pos x 30 rows x 7 groups of 8 bf16 (uint4 global loads)
    for (int idx = tid; idx < 1890; idx += 256) {
        int i = idx / 210, rem = idx - i * 210;
        int r = rem / 7, g = rem - r * 7;
        int h = h0 - 1 + r;
        uint4 v = {0u, 0u, 0u, 0u};
        if (h >= 0 && h < Hh)
            v = *(const uint4*)&feat[(((size_t)i * Bn + b) * Cc + c) * HWn + h * Ww + 8 * g];
        unsigned int* dst = (unsigned int*)&ft[i][r][2 + 8 * g];
        dst[0] = v.x; dst[1] = v.y; dst[2] = v.z; dst[3] = v.w;
    }
    // edge zeros: cols 0,1 (w=-2,-1) and 58,59 (w=56,57)
    for (int idx = tid; idx < 1080; idx += 256) {
        int i = idx / 120, rem = idx - i * 120;
        int r = rem >> 2, e = rem & 3;
        int col = (e < 2) ? e : 56 + e;
        ft[i][r][col] = 0;
    }
    __syncthreads();

    if (tid < 196) {
        const int row = tid / 7, seg = tid - row * 7;
        const int w0 = 8 * seg;
        const int hw = (h0 + row) * Ww + w0;

        // ---- softmax over 9 positions, 8 px ----
        float lg[9][8];
        const __hip_bfloat16* lbase = logits + ((size_t)b * CKK + c * 9) * HWn + hw;
#pragma unroll
        for (int i = 0; i < 9; i++) {
            uint4 lv = *(const uint4*)&lbase[(size_t)i * HWn];
            lg[i][0] = blo(lv.x); lg[i][1] = bhi(lv.x);
            lg[i][2] = blo(lv.y); lg[i][3] = bhi(lv.y);
            lg[i][4] = blo(lv.z); lg[i][5] = bhi(lv.z);
            lg[i][6] = blo(lv.w); lg[i][7] = bhi(lv.w);
        }
        float mx[8], sum[8];
#pragma unroll
        for (int p = 0; p < 8; p++) {
            mx[p] = lg[0][p];
#pragma unroll
            for (int i = 1; i < 9; i++) mx[p] = fmaxf(mx[p], lg[i][p]);
            sum[p] = 0.f;
        }
#pragma unroll
        for (int i = 0; i < 9; i++)
#pragma unroll
            for (int p = 0; p < 8; p++) {
                lg[i][p] = __expf(lg[i][p] - mx[p]);
                sum[p] += lg[i][p];
            }

        // ---- conv2 + weighted aggregation ----
        float oacc[8] = {};
#pragma unroll
        for (int i = 0; i < 9; i++) {
            const float* wp = w2 + ((size_t)i * Cc + c) * 9;
            float wgt[9];
#pragma unroll
            for (int j = 0; j < 9; j++) wgt[j] = wp[j];
            float cacc[8] = {};
#pragma unroll
            for (int u = 0; u < 3; u++) {
                const unsigned short* fr = &ft[i][row + u][w0];
                uint4 a = *(const uint4*)fr;        // cols w0..w0+7 (tile)
                uint2 bq = *(const uint2*)(fr + 8); // cols w0+8..w0+11
                float wf[11];
                wf[1] = bhi(a.x);
                wf[2] = blo(a.y);  wf[3] = bhi(a.y);
                wf[4] = blo(a.z);  wf[5] = bhi(a.z);
                wf[6] = blo(a.w);  wf[7] = bhi(a.w);
                wf[8] = blo(bq.x); wf[9] = bhi(bq.x);
                wf[10] = blo(bq.y);
#pragma unroll
                for (int v = 0; v < 3; v++) {
                    float wv = wgt[u * 3 + v];
#pragma unroll
                    for (int p = 0; p < 8; p++)
                        cacc[p] += wf[p + v + 1] * wv;
                }
            }
#pragma unroll
            for (int p = 0; p < 8; p++) oacc[p] += cacc[p] * lg[i][p];
        }

        float* obase = out + ((size_t)(b * Cc + c)) * HWn + hw;
        float4 o0, o1;
        o0.x = oacc[0] * __builtin_amdgcn_rcpf(sum[0]);
        o0.y = oacc[1] * __builtin_amdgcn_rcpf(sum[1]);
        o0.z = oacc[2] * __builtin_amdgcn_rcpf(sum[2]);
        o0.w = oacc[3] * __builtin_amdgcn_rcpf(sum[3]);
        o1.x = oacc[4] * __builtin_amdgcn_rcpf(sum[4]);
        o1.y = oacc[5] * __builtin_amdgcn_rcpf(sum[5]);
        o1.z = oacc[6] * __builtin_amdgcn_rcpf(sum[6]);
        o1.w = oacc[7] * __builtin_amdgcn_rcpf(sum[7]);
        *(float4*)&obase[0] = o0;
        *(float4*)&obase[4] = o1;
    }
}

// ---------------------------------------------------------------------------
extern "C" void kernel_launch(void* const* d_in, const int* in_sizes, int n_in,
                              void* d_out, int out_size, void* d_ws, size_t ws_size,
                              hipStream_t stream)
{
    const float* x    = (const float*)d_in[0];
    const float* fc_w = (const float*)d_in[1];
    const float* w1   = (const float*)d_in[2];
    const float* w2   = (const float*)d_in[3];
    float* out = (float*)d_out;

    char* ws = (char*)d_ws;
    __hip_bfloat16* logits = (__hip_bfloat16*)ws;
    char* region2 = ws + (size_t)Bn * CKK * HWn * 2;
    __hip_bfloat16* feat = (__hip_bfloat16*)region2;
    _Float16* xt    = (_Float16*)region2;
    _Float16* fcw16 = (_Float16*)(region2 + (size_t)GN * GK * 2);

    cast_fcw_kernel<<<(GM * GK / 4 + 255) / 256, 256, 0, stream>>>(fc_w, fcw16);
    transpose_cast_kernel<<<dim3(HWn / 64, GK / 32, Bn), 256, 0, stream>>>(x, xt);
    gemm_mfma_kernel<<<dim3(GN / 128, GM / 128), 256, 0, stream>>>(fcw16, xt, logits);
    conv1_kernel<<<dim3(Cc, 2, Bn), 256, 0, stream>>>(x, w1, feat);
    conv2_agg_kernel<<<dim3(Cc, 2, Bn), 256, 0, stream>>>(feat, logits, w2, out);
}